// Round 1
// baseline (123.599 us; speedup 1.0000x reference)
//
#include <hip/hip_runtime.h>

// B=4, C=256, CR=64, H=W=64, K=7, KK=49, GROUPS=16, GC=16
#define BN_EPS 1e-5f

typedef __bf16 bf16_t;
typedef __bf16 bf16x8 __attribute__((ext_vector_type(8)));
typedef __bf16 bf16x4 __attribute__((ext_vector_type(4)));
typedef __bf16 bf16x2 __attribute__((ext_vector_type(2)));
typedef float  floatx4 __attribute__((ext_vector_type(4)));

#define MFMA16(a, b, c) __builtin_amdgcn_mfma_f32_16x16x32_bf16((a), (b), (c), 0, 0, 0)

// ws layout: only xT (16384 px x 64 ch bf16 = 2 MB)
#define XT_OFF 0

// ---------------------------------------------------------------------------
// K1 conv1: one block per (b,h), 512 threads (8 waves = 2/SIMD for latency
// hiding; prev version ran 256 thr = 1 wave/SIMD and was latency-bound).
// w1 is NOT staged in LDS anymore: A-fragments are loaded直接 from global
// (64 KB, L2-hot across all 256 blocks) as float4 pairs and BN-folded in
// registers (iv hoisted once per lane). Only the guide transpose gTs stays
// in LDS (33.8 KB, was 67.6 -> occupancy doubles).
//   gTs[p][c] = bf16(guide[b][c][h][p])
// MFMA x[64o][64p] = (w1*iv) . gTs; +bias, ReLU; store xT[bp][o].
// 8 waves: wv&3 = o-tile (16 ch), wv>>2 = p-half (32 px, 2 nt tiles).
// ---------------------------------------------------------------------------
#define GTP 264

__global__ __launch_bounds__(512) void conv1_k(
    const float* __restrict__ guide, const float* __restrict__ w1,
    const float* __restrict__ gamma, const float* __restrict__ beta,
    const float* __restrict__ mean,  const float* __restrict__ var,
    bf16_t* __restrict__ xT)
{
    __shared__ __attribute__((aligned(16))) bf16_t gTs[64 * GTP];  // 33.8 KB
    const int b = blockIdx.x >> 6, h = blockIdx.x & 63;
    const int t = threadIdx.x;

    // stage guide row transposed: coalesced dword reads (lanes = p)
    const float* gsrc = guide + (size_t)b * 256 * 4096 + h * 64;
#pragma unroll
    for (int i = 0; i < 16; ++i) {
        const int idx = i * 512 + t;       // 8192 units = 128 c2 x 64 p
        const int c2 = idx >> 6, p = idx & 63;
        const float g0 = gsrc[(size_t)(2 * c2) * 4096 + p];
        const float g1 = gsrc[(size_t)(2 * c2 + 1) * 4096 + p];
        bf16x2 pk; pk[0] = (bf16_t)g0; pk[1] = (bf16_t)g1;
        *(bf16x2*)&gTs[p * GTP + 2 * c2] = pk;
    }
    __syncthreads();

    const int wv = t >> 6, ln = t & 63, l15 = ln & 15, q = ln >> 4;
    const int ot = wv & 3;          // o-tile: channels ot*16 .. +16
    const int ph = wv >> 2;         // p-half: pixels ph*32 .. +32
    const int o = ot * 16 + l15;    // A-row this lane reads
    const float iv = gamma[o] * rsqrtf(var[o] + BN_EPS);

    floatx4 acc[2] = {};
#pragma unroll
    for (int ks = 0; ks < 8; ++ks) {
        const float* wp = w1 + o * 256 + ks * 32 + q * 8;
        const float4 a0 = *(const float4*)(wp);
        const float4 a1 = *(const float4*)(wp + 4);
        bf16x8 a;
        a[0] = (bf16_t)(a0.x * iv); a[1] = (bf16_t)(a0.y * iv);
        a[2] = (bf16_t)(a0.z * iv); a[3] = (bf16_t)(a0.w * iv);
        a[4] = (bf16_t)(a1.x * iv); a[5] = (bf16_t)(a1.y * iv);
        a[6] = (bf16_t)(a1.z * iv); a[7] = (bf16_t)(a1.w * iv);
#pragma unroll
        for (int nt = 0; nt < 2; ++nt) {
            const bf16x8 bb = *(const bf16x8*)&gTs[(ph * 32 + nt * 16 + l15) * GTP + ks * 32 + q * 8];
            acc[nt] = MFMA16(a, bb, acc[nt]);
        }
    }
    // bias (BN) computed inline per output row
    float bi[4];
#pragma unroll
    for (int j = 0; j < 4; ++j) {
        const int o2 = ot * 16 + q * 4 + j;
        const float iv2 = gamma[o2] * rsqrtf(var[o2] + BN_EPS);
        bi[j] = beta[o2] - mean[o2] * iv2;
    }
#pragma unroll
    for (int nt = 0; nt < 2; ++nt) {
        const int p = ph * 32 + nt * 16 + l15;
        bf16x4 v;
#pragma unroll
        for (int j = 0; j < 4; ++j) v[j] = (bf16_t)fmaxf(acc[nt][j] + bi[j], 0.f);
        *(bf16x4*)(xT + ((size_t)(b * 64 + h) * 64 + p) * 64 + ot * 16 + q * 4) = v;
    }
}

// ---------------------------------------------------------------------------
// K2 conv2+agg fused: one block = (g, b, h-pair); blockIdx = (b*32+hp)*16 + g
// (XCD = g%8 -> per-XCD feat slice ~2 MB, L2-resident).
//  Parallel (no dependency, single barrier after):
//   - stage fs[16ch][8 rows][72 w] fp32, zero-padded borders (36 KB)
//   - MFMA wg[49k x 128px] = w2[g] . xT  (A-frags: fp32 w2 global -> cvt in
//     regs; B-frags: direct global xT, c-contiguous), +b2 -> wgs bf16 (13.3 KB)
//  barrier
//   - branchless agg: thread = (wq, r, cp) -> 2ch x 4w; 392 FMA from LDS;
//     residual from fs (exact fp32); coalesced float4 stores.
// LDS 49.3 KB -> 3 blocks/CU. Grid 2048.
// ---------------------------------------------------------------------------
#define FSR 72     // fs row pitch (floats): [4 pad][64 w][4 pad]
#define FSC 576    // fs channel pitch = 8*72
#define WGP 136    // wgs row pitch (bf16)

__global__ __launch_bounds__(256) void fused_k(
    const bf16_t* __restrict__ xT, const float* __restrict__ w2,
    const float* __restrict__ b2,  const float* __restrict__ feat,
    float* __restrict__ out)
{
    __shared__ __attribute__((aligned(16))) float  fs[16 * FSC];   // 36.0 KB
    __shared__ __attribute__((aligned(16))) bf16_t wgs[49 * WGP];  // 13.3 KB

    const int g = blockIdx.x & 15;
    const int rest = blockIdx.x >> 4;      // 0..127
    const int b = rest >> 5, hp = rest & 31;
    const int h0 = hp * 2;
    const int t = threadIdx.x;
    const int wv = t >> 6, ln = t & 63, l15 = ln & 15, q = ln >> 4;

    // ---- stage fs: 16 ch x 8 rows x 18 quads, zero-padded ----
#pragma unroll
    for (int i = 0; i < 9; ++i) {
        const int u = i * 256 + t;         // 2304 quads
        const int c = u / 144, rem = u - c * 144;
        const int rr = rem / 18, qq = rem - rr * 18;
        const int hh = h0 - 3 + rr;
        float4 v = {0.f, 0.f, 0.f, 0.f};
        if (qq >= 1 && qq <= 16 && hh >= 0 && hh < 64)
            v = *(const float4*)(feat + ((size_t)(b * 256 + g * 16 + c) * 64 + hh) * 64 + (qq - 1) * 4);
        *(float4*)&fs[c * FSC + rr * FSR + qq * 4] = v;
    }

    // ---- MFMA: wg[49 x 128] = w2[g] . xT ; A-frags cvt'd from fp32 in regs ----
    {
        floatx4 acc[4][2] = {};
        const bf16_t* brow = xT + ((size_t)(b * 64 + h0) * 64 + wv * 32) * 64;
#pragma unroll
        for (int ks = 0; ks < 2; ++ks) {
            bf16x8 bfr[2];
            bfr[0] = *(const bf16x8*)(brow + l15 * 64 + ks * 32 + q * 8);
            bfr[1] = *(const bf16x8*)(brow + (16 + l15) * 64 + ks * 32 + q * 8);
#pragma unroll
            for (int mt = 0; mt < 4; ++mt) {
                int row = mt * 16 + l15; if (row > 48) row = 48;  // pad rows never stored
                const float* wp = w2 + (size_t)(g * 49 + row) * 64 + ks * 32 + q * 8;
                const float4 a0 = *(const float4*)(wp);
                const float4 a1 = *(const float4*)(wp + 4);
                bf16x8 a;
                a[0] = (bf16_t)a0.x; a[1] = (bf16_t)a0.y; a[2] = (bf16_t)a0.z; a[3] = (bf16_t)a0.w;
                a[4] = (bf16_t)a1.x; a[5] = (bf16_t)a1.y; a[6] = (bf16_t)a1.z; a[7] = (bf16_t)a1.w;
                acc[mt][0] = MFMA16(a, bfr[0], acc[mt][0]);
                acc[mt][1] = MFMA16(a, bfr[1], acc[mt][1]);
            }
        }
#pragma unroll
        for (int mt = 0; mt < 4; ++mt) {
#pragma unroll
            for (int j = 0; j < 4; ++j) {
                const int k = mt * 16 + q * 4 + j;
                if (k < 49) {
                    const float bias = b2[g * 49 + k];
                    wgs[k * WGP + wv * 32 + l15]      = (bf16_t)(acc[mt][0][j] + bias);
                    wgs[k * WGP + wv * 32 + 16 + l15] = (bf16_t)(acc[mt][1][j] + bias);
                }
            }
        }
    }
    __syncthreads();

    // ---- agg: thread = (wq, r, cp) -> 2 ch x 4 w, branchless di loop ----
    const int wq = t & 15, r = (t >> 4) & 1, cp = t >> 5;   // cp in [0,8)
    const int w0 = wq * 4;
    const int ch0 = cp * 2;

    float acc[2][4] = {};
#pragma unroll
    for (int di = 0; di < 7; ++di) {
        const int ri = r + di;             // 0..7, zero-padded rows
        float f0[12], f1[12];
        {
            const float* p0 = &fs[ch0 * FSC + ri * FSR + w0];
            const float* p1 = p0 + FSC;
#pragma unroll
            for (int qj = 0; qj < 3; ++qj) {
                const floatx4 a = *(const floatx4*)(p0 + qj * 4);
                const floatx4 bq = *(const floatx4*)(p1 + qj * 4);
#pragma unroll
                for (int j = 0; j < 4; ++j) { f0[qj * 4 + j] = a[j]; f1[qj * 4 + j] = bq[j]; }
            }
        }
        const bf16_t* wrow = &wgs[(di * 7) * WGP + r * 64 + w0];
#pragma unroll
        for (int dj = 0; dj < 7; ++dj) {
            const bf16x4 wb = *(const bf16x4*)(wrow + dj * WGP);
#pragma unroll
            for (int x = 0; x < 4; ++x) {
                const float wf = (float)wb[x];
                acc[0][x] = fmaf(wf, f0[x + dj + 1], acc[0][x]);
                acc[1][x] = fmaf(wf, f1[x + dj + 1], acc[1][x]);
            }
        }
    }

    // residual from staged fp32 tile (row r+3 == h0+r), + store
#pragma unroll
    for (int c = 0; c < 2; ++c) {
        const floatx4 res = *(const floatx4*)&fs[(ch0 + c) * FSC + (r + 3) * FSR + 4 + w0];
        const size_t ob = ((size_t)(b * 256 + g * 16 + ch0 + c) * 64 + h0 + r) * 64 + w0;
        float4 o;
        o.x = acc[c][0] + res[0]; o.y = acc[c][1] + res[1];
        o.z = acc[c][2] + res[2]; o.w = acc[c][3] + res[3];
        *(float4*)(out + ob) = o;
    }
}

extern "C" void kernel_launch(void* const* d_in, const int* in_sizes, int n_in,
                              void* d_out, int out_size, void* d_ws, size_t ws_size,
                              hipStream_t stream) {
    const float* feature = (const float*)d_in[0];
    const float* guide   = (const float*)d_in[1];
    const float* w1      = (const float*)d_in[2];
    const float* gamma   = (const float*)d_in[3];
    const float* beta    = (const float*)d_in[4];
    const float* mean    = (const float*)d_in[5];
    const float* var     = (const float*)d_in[6];
    const float* w2      = (const float*)d_in[7];
    const float* b2      = (const float*)d_in[8];
    float* out = (float*)d_out;

    bf16_t* xT = (bf16_t*)((char*)d_ws + XT_OFF);

    conv1_k<<<256, 512, 0, stream>>>(guide, w1, gamma, beta, mean, var, xT);
    fused_k<<<2048, 256, 0, stream>>>(xT, w2, b2, feature, out);
}